// Round 1
// baseline (253.301 us; speedup 1.0000x reference)
//
#include <hip/hip_runtime.h>
#include <stdint.h>

// Problem constants (reference file)
#define B_SZ 16
#define L_SZ 1024
#define D_SZ 512
#define E_SZ 8
#define DFF_SZ 2048

typedef short bf16x8 __attribute__((ext_vector_type(8)));
typedef float f32x4 __attribute__((ext_vector_type(4)));

__device__ __forceinline__ unsigned short f2bf(float f) {
  unsigned int u = __float_as_uint(f);
  u += 0x7fffu + ((u >> 16) & 1u);   // round-to-nearest-even
  return (unsigned short)(u >> 16);
}

__device__ __forceinline__ void async_cp16(void* lds, const void* g) {
  __builtin_amdgcn_global_load_lds(
      (const __attribute__((address_space(1))) void*)g,
      (__attribute__((address_space(3))) void*)lds, 16, 0, 0);
}

// ---------------------------------------------------------------------------
// Kernel 1: router — top1 per sample + balance loss
// ---------------------------------------------------------------------------
__global__ void router_kernel(const int* __restrict__ view_ids,
                              const int* __restrict__ visit_ids,
                              const float* __restrict__ rview,
                              const float* __restrict__ rvisit,
                              int* __restrict__ top1,
                              float* __restrict__ loss_out) {
  __shared__ float probs[B_SZ][E_SZ];
  const int t = threadIdx.x;
  if (t < B_SZ) {
    const int vi = view_ids[t];
    const int si = visit_ids[t];
    float lg[E_SZ];
#pragma unroll
    for (int e = 0; e < E_SZ; ++e)
      lg[e] = rview[vi * E_SZ + e] + rvisit[si * E_SZ + e];
    // first-occurrence argmax (matches jnp.argmax)
    int am = 0;
    float bm = lg[0];
#pragma unroll
    for (int e = 1; e < E_SZ; ++e)
      if (lg[e] > bm) { bm = lg[e]; am = e; }
    top1[t] = am;
    float s = 0.f;
#pragma unroll
    for (int e = 0; e < E_SZ; ++e) {
      const float p = expf(lg[e] - bm);
      probs[t][e] = p;
      s += p;
    }
    const float inv = 1.f / s;
#pragma unroll
    for (int e = 0; e < E_SZ; ++e) probs[t][e] *= inv;
  }
  __syncthreads();
  if (t == 0) {
    float loss = 0.f;
#pragma unroll
    for (int e = 0; e < E_SZ; ++e) {
      float ld = 0.f;
      for (int b = 0; b < B_SZ; ++b) ld += probs[b][e];
      ld *= (1.0f / B_SZ);
      loss -= ld * logf(ld);
    }
    *loss_out = loss;
  }
}

// ---------------------------------------------------------------------------
// Kernel 2: cast x fp32 -> bf16, vectorized float4 -> ushort4
// ---------------------------------------------------------------------------
__global__ void cast_x_kernel(const float* __restrict__ x,
                              unsigned short* __restrict__ xb) {
  const int i = blockIdx.x * 256 + threadIdx.x;  // exact grid, no bounds check
  const float4 v = reinterpret_cast<const float4*>(x)[i];
  ushort4 o;
  o.x = f2bf(v.x); o.y = f2bf(v.y); o.z = f2bf(v.z); o.w = f2bf(v.w);
  reinterpret_cast<ushort4*>(xb)[i] = o;
}

// ---------------------------------------------------------------------------
// Kernel 3: transpose + cast: src [E][K][N] fp32 -> dst [E][N][K] bf16
// 64x64 tiles through LDS, both global phases coalesced.
// ---------------------------------------------------------------------------
__global__ void transpose_cast_kernel(const float* __restrict__ src,
                                      unsigned short* __restrict__ dst,
                                      int K, int N) {
  __shared__ float tile[64][65];   // +1 pad: conflict-free column read
  const int e = blockIdx.z;
  const int n0 = blockIdx.x * 64;
  const int k0 = blockIdx.y * 64;
  const int t = threadIdx.x;       // 256
  const int c = t & 63;
  const int r4 = t >> 6;           // 0..3
  const float* s = src + ((size_t)e * K + k0) * N + n0;
#pragma unroll
  for (int it = 0; it < 16; ++it) {
    const int k = it * 4 + r4;
    tile[k][c] = s[(size_t)k * N + c];
  }
  __syncthreads();
  unsigned short* d = dst + ((size_t)e * N + n0) * K + k0;
#pragma unroll
  for (int it = 0; it < 16; ++it) {
    const int n = it * 4 + r4;
    d[(size_t)n * K + c] = f2bf(tile[c][n]);
  }
}

// ---------------------------------------------------------------------------
// Kernel 4: grouped bf16 MFMA GEMM, 128x128 tile, BK=64, double-buffered LDS,
// global_load_lds(16B) staging with XOR-swizzle (both-sides: pre-swizzled
// global source granule + swizzled ds_read granule; rule 21).
//   A  : [B][M][K] bf16 (row-major)
//   BT : [E][N][K] bf16 (row-major = B transposed)
//   out: [B][M][N] (bf16 if OUT_BF16 else f32), += bias[e][N], optional relu
// 4 waves (2x2), each wave 64x64 = 4x4 fragments of mfma_f32_16x16x32_bf16.
// ---------------------------------------------------------------------------
template <bool RELU, bool OUT_BF16>
__global__ __launch_bounds__(256, 2) void gemm_kernel(
    const unsigned short* __restrict__ A,
    const unsigned short* __restrict__ BT,
    const float* __restrict__ bias,
    const int* __restrict__ top1,
    void* __restrict__ Out,
    int M, int N, int K) {
  __shared__ __align__(16) unsigned short sm[2][2][128 * 64];  // 64 KiB

  const int bz = blockIdx.z;           // sample
  const int e = top1[bz];              // expert
  const int n0 = blockIdx.x * 128;
  const int m0 = blockIdx.y * 128;

  const int t = threadIdx.x;
  const int lane = t & 63;
  const int wid = t >> 6;
  const int wr = wid >> 1, wc = wid & 1;
  const int lr = lane & 15, lg = lane >> 4;

  // --- staging addresses: thread t stages 16B granule (row=t>>3, g=t&7) of a
  // 32-row chunk; LDS dest is linear (t*16), global source granule is
  // pre-swizzled g ^ (row&7) so swizzled ds_reads see the right data.
  const size_t Kb = (size_t)K * 2;     // bytes per row
  const int srow = t >> 3;             // 0..31
  const int sgr = (t & 7) ^ (srow & 7);
  const char* aSrc = (const char*)(A + (size_t)bz * M * K + (size_t)m0 * K) +
                     (size_t)srow * Kb + sgr * 16;
  const char* bSrc = (const char*)(BT + (size_t)e * N * K + (size_t)n0 * K) +
                     (size_t)srow * Kb + sgr * 16;

  f32x4 acc[4][4] = {};

  const int nk = K >> 6;

  auto stage = [&](int buf, int kt) {
    char* la = (char*)&sm[buf][0][0];
    char* lb = (char*)&sm[buf][1][0];
    const size_t kofs = (size_t)kt * 128;
#pragma unroll
    for (int c = 0; c < 4; ++c) {
      async_cp16(la + c * 4096 + t * 16, aSrc + kofs + (size_t)c * 32 * Kb);
      async_cp16(lb + c * 4096 + t * 16, bSrc + kofs + (size_t)c * 32 * Kb);
    }
  };

  stage(0, 0);
  __syncthreads();

  for (int kt = 0; kt < nk; ++kt) {
    const int cur = kt & 1;
    if (kt + 1 < nk) stage(cur ^ 1, kt + 1);  // prefetch next K-tile
    const char* la = (const char*)&sm[cur][0][0];
    const char* lb = (const char*)&sm[cur][1][0];
#pragma unroll
    for (int ks = 0; ks < 2; ++ks) {   // two k=32 sub-steps of the BK=64 tile
      bf16x8 af[4], bg[4];
#pragma unroll
      for (int i = 0; i < 4; ++i) {
        const int row = wr * 64 + i * 16 + lr;
        af[i] = *(const bf16x8*)(la + row * 128 +
                                 (((ks * 4 + lg) ^ (row & 7)) << 4));
      }
#pragma unroll
      for (int j = 0; j < 4; ++j) {
        const int row = wc * 64 + j * 16 + lr;
        bg[j] = *(const bf16x8*)(lb + row * 128 +
                                 (((ks * 4 + lg) ^ (row & 7)) << 4));
      }
#pragma unroll
      for (int i = 0; i < 4; ++i)
#pragma unroll
        for (int j = 0; j < 4; ++j)
          acc[i][j] = __builtin_amdgcn_mfma_f32_16x16x32_bf16(
              af[i], bg[j], acc[i][j], 0, 0, 0);
    }
    __syncthreads();   // drains vmcnt too: next-tile stage complete, reads done
  }

  // --- epilogue: C/D mapping col=lane&15, row=(lane>>4)*4+reg (m89-verified)
  const float* bb = bias + (size_t)e * N + n0;
  unsigned short* ho = (unsigned short*)Out;
  float* fo = (float*)Out;
  const size_t obase = (size_t)bz * M * N + (size_t)m0 * N + n0;
#pragma unroll
  for (int j = 0; j < 4; ++j) {
    const int col = wc * 64 + j * 16 + lr;
    const float bv = bb[col];
#pragma unroll
    for (int i = 0; i < 4; ++i) {
      const int row0 = wr * 64 + i * 16 + lg * 4;
#pragma unroll
      for (int r = 0; r < 4; ++r) {
        float v = acc[i][j][r] + bv;
        if (RELU) v = fmaxf(v, 0.0f);
        const size_t o = obase + (size_t)(row0 + r) * N + col;
        if (OUT_BF16) ho[o] = f2bf(v);
        else fo[o] = v;
      }
    }
  }
}

// ---------------------------------------------------------------------------
// Launch
// ---------------------------------------------------------------------------
extern "C" void kernel_launch(void* const* d_in, const int* in_sizes, int n_in,
                              void* d_out, int out_size, void* d_ws,
                              size_t ws_size, hipStream_t stream) {
  const float* x = (const float*)d_in[0];
  const int* view_ids = (const int*)d_in[1];
  const int* visit_ids = (const int*)d_in[2];
  const float* rview = (const float*)d_in[3];
  const float* rvisit = (const float*)d_in[4];
  const float* W1 = (const float*)d_in[5];
  const float* b1 = (const float*)d_in[6];
  const float* W2 = (const float*)d_in[7];
  const float* b2 = (const float*)d_in[8];
  float* out = (float*)d_out;

  // workspace layout (ws re-poisoned every call; everything rewritten below)
  char* ws = (char*)d_ws;
  int* top1 = (int*)ws;                                              //    64 B
  unsigned short* x_bf = (unsigned short*)(ws + 256);                // 16 MiB
  unsigned short* w1t = (unsigned short*)(ws + 256 + 16777216L);     // 16 MiB
  unsigned short* w2t = (unsigned short*)(ws + 256 + 2 * 16777216L); // 16 MiB
  unsigned short* h_bf = (unsigned short*)(ws + 256 + 3 * 16777216L);// 64 MiB

  // 1. router: top1 + balance loss (loss goes to d_out[B*L*D])
  router_kernel<<<1, 64, 0, stream>>>(view_ids, visit_ids, rview, rvisit, top1,
                                      out + (size_t)B_SZ * L_SZ * D_SZ);
  // 2. x -> bf16   (B*L*D = 8388608 floats, 4/thread)
  cast_x_kernel<<<8192, 256, 0, stream>>>(x, x_bf);
  // 3. W1 [E][D][DFF] -> [E][DFF][D] bf16 ; W2 [E][DFF][D] -> [E][D][DFF] bf16
  transpose_cast_kernel<<<dim3(DFF_SZ / 64, D_SZ / 64, E_SZ), 256, 0, stream>>>(
      W1, w1t, D_SZ, DFF_SZ);
  transpose_cast_kernel<<<dim3(D_SZ / 64, DFF_SZ / 64, E_SZ), 256, 0, stream>>>(
      W2, w2t, DFF_SZ, D_SZ);
  // 4. h = relu(x @ W1[e] + b1[e])  -> bf16   (M=1024,N=2048,K=512 per sample)
  gemm_kernel<true, true>
      <<<dim3(DFF_SZ / 128, L_SZ / 128, B_SZ), 256, 0, stream>>>(
          x_bf, w1t, b1, top1, (void*)h_bf, L_SZ, DFF_SZ, D_SZ);
  // 5. out = h @ W2[e] + b2[e]      -> f32    (M=1024,N=512,K=2048 per sample)
  gemm_kernel<false, false>
      <<<dim3(D_SZ / 128, L_SZ / 128, B_SZ), 256, 0, stream>>>(
          h_bf, w2t, b2, top1, (void*)out, L_SZ, D_SZ, DFF_SZ);
}